// Round 4
// baseline (381.020 us; speedup 1.0000x reference)
//
#include <hip/hip_runtime.h>
#include <hip/hip_cooperative_groups.h>
#include <math.h>

namespace cg = cooperative_groups;

#define WH     256
#define NDEPTH 8
#define NBATCH 1024
#define NB     8            // batch elements per block
#define PLANE  (WH * WH)    // 65536

// ---------------------------------------------------------------------------
// Single cooperative kernel: 256 blocks x 512 threads.
//
// Phase A: transpose all 4 arrays [d][w][h] -> ws[arr][d][h][w].
//          512 tiles of 64x64; each block does 2 tiles via a 64x65 LDS tile.
// grid.sync()
// Phase B: prop. Block (br,bg): br = XCD-pinned branch, bg = 8-batch group.
//          Wave ws owns h in [32ws,32ws+32); lane owns w = 4*lane..4*lane+3.
//          2h chunks, double-buffered (32 buffer VGPRs -> no spill),
//          prefetch crosses depth boundaries. Per depth: LDS max-combine
//          across 8 waves, then 64-lane shuffle min over w.
// ---------------------------------------------------------------------------
__global__ __launch_bounds__(512, 2) void fused_k(const float* __restrict__ M1,
                                                  const float* __restrict__ B1,
                                                  const float* __restrict__ M2,
                                                  const float* __restrict__ B2,
                                                  const float* __restrict__ val,
                                                  float* __restrict__ ws,
                                                  float* __restrict__ out) {
    __shared__ __align__(16) float smem[8 * NB * WH];  // 64 KB, reused A->B
    __shared__ float qs[NB];
    const int t   = threadIdx.x;
    const int bid = blockIdx.x;

    // ---------------- Phase A: transpose ----------------
    {
        float (*tile)[65] = (float (*)[65])smem;   // 64x65 = 16.6 KB of smem
#pragma unroll
        for (int ti = 0; ti < 2; ++ti) {
            const int tl  = bid * 2 + ti;          // 0..511
            const int arr = tl >> 7;
            const int d   = (tl >> 4) & 7;
            const int ht  = (tl >> 2) & 3;
            const int wt  = tl & 3;
            const float* src = (arr == 0) ? M1 : (arr == 1) ? B1 : (arr == 2) ? M2 : B2;
            const float* s = src + d * PLANE;
            float*       o = ws + ((size_t)arr * NDEPTH + d) * PLANE;

            if (ti) __syncthreads();               // tile reuse guard
#pragma unroll
            for (int p = 0; p < 2; ++p) {          // read: lanes along h
                const int r = (t >> 4) + p * 32;   // w-local 0..63
                const int c = (t & 15) * 4;        // h-local
                const float4 v = *(const float4*)(s + (wt * 64 + r) * WH + ht * 64 + c);
                tile[r][c + 0] = v.x; tile[r][c + 1] = v.y;
                tile[r][c + 2] = v.z; tile[r][c + 3] = v.w;
            }
            __syncthreads();
#pragma unroll
            for (int p = 0; p < 2; ++p) {          // write: lanes along w
                const int hr = (t >> 4) + p * 32;  // h-local 0..63
                const int c  = (t & 15) * 4;       // w-local
                float4 v;
                v.x = tile[c + 0][hr]; v.y = tile[c + 1][hr];
                v.z = tile[c + 2][hr]; v.w = tile[c + 3][hr];
                *(float4*)(o + (ht * 64 + hr) * WH + wt * 64 + c) = v;
            }
        }
    }
    cg::this_grid().sync();

    // ---------------- Phase B: propagation ----------------
    const int g     = bid >> 3;
    const int x     = bid & 7;
    const int br    = x >> 2;               // branch -> XCD half
    const int bg    = g * 4 + (x & 3);      // 0..127
    const int wave  = t >> 6;               // 0..7
    const int lane  = t & 63;
    const int hbase = wave * 32;

    const float4* __restrict__ Mb = (const float4*)(ws + (size_t)(br ? 2 : 0) * NDEPTH * PLANE);
    const float4* __restrict__ Bb = (const float4*)(ws + (size_t)(br ? 3 : 1) * NDEPTH * PLANE);

    float q[NB];
#pragma unroll
    for (int nb = 0; nb < NB; ++nb) q[nb] = val[bg * NB + nb];   // block-uniform

    float* part = smem;   // [8 waves][NB][WH]

    float4 m[2][2], b[2][2];
    {   // preload chunk 0 of depth 0 (rows hbase, hbase+1)
        const float4* Mp = Mb + hbase * 64 + lane;
        const float4* Bp = Bb + hbase * 64 + lane;
        m[0][0] = Mp[0]; m[0][1] = Mp[64];
        b[0][0] = Bp[0]; b[0][1] = Bp[64];
    }

    for (int d = 0; d < NDEPTH; ++d) {
        float acc[NB][4];
#pragma unroll
        for (int nb = 0; nb < NB; ++nb)
#pragma unroll
            for (int c = 0; c < 4; ++c) acc[nb][c] = -INFINITY;

#pragma unroll
        for (int ch = 0; ch < 16; ++ch) {          // 2 h per chunk
            const int cur = ch & 1, nxt = cur ^ 1;
            const int nchunk = d * 16 + ch + 1;    // flat next-chunk id
            if (nchunk < NDEPTH * 16) {            // prefetch (crosses depths)
                const int d2 = nchunk >> 4;
                const int c2 = nchunk & 15;
                const float4* Mp = Mb + d2 * (PLANE / 4) + (hbase + c2 * 2) * 64 + lane;
                const float4* Bp = Bb + d2 * (PLANE / 4) + (hbase + c2 * 2) * 64 + lane;
                m[nxt][0] = Mp[0]; m[nxt][1] = Mp[64];
                b[nxt][0] = Bp[0]; b[nxt][1] = Bp[64];
            }
            const float4 m0 = m[cur][0], m1 = m[cur][1];
            const float4 b0 = b[cur][0], b1 = b[cur][1];
#pragma unroll
            for (int nb = 0; nb < NB; ++nb) {
                const float qv = q[nb];
                // max(acc, max(s0,s1)) folds to v_max3_f32: 1.5 instr/element
                acc[nb][0] = fmaxf(acc[nb][0], fmaxf(fmaf(qv, m0.x, b0.x), fmaf(qv, m1.x, b1.x)));
                acc[nb][1] = fmaxf(acc[nb][1], fmaxf(fmaf(qv, m0.y, b0.y), fmaf(qv, m1.y, b1.y)));
                acc[nb][2] = fmaxf(acc[nb][2], fmaxf(fmaf(qv, m0.z, b0.z), fmaf(qv, m1.z, b1.z)));
                acc[nb][3] = fmaxf(acc[nb][3], fmaxf(fmaf(qv, m0.w, b0.w), fmaf(qv, m1.w, b1.w)));
            }
        }

        // stage per-wave partial maxes: part[wave][nb][w]
#pragma unroll
        for (int nb = 0; nb < NB; ++nb)
            *(float4*)&part[(wave * NB + nb) * WH + lane * 4] =
                make_float4(acc[nb][0], acc[nb][1], acc[nb][2], acc[nb][3]);
        __syncthreads();

        // wave `wave` reduces batch nb==wave: max over 8 waves, min over 256 w
        {
            float4 v = *(const float4*)&part[(0 * NB + wave) * WH + lane * 4];
#pragma unroll
            for (int s2 = 1; s2 < 8; ++s2) {
                const float4 w4 = *(const float4*)&part[(s2 * NB + wave) * WH + lane * 4];
                v.x = fmaxf(v.x, w4.x); v.y = fmaxf(v.y, w4.y);
                v.z = fmaxf(v.z, w4.z); v.w = fmaxf(v.w, w4.w);
            }
            float r = fminf(fminf(v.x, v.y), fminf(v.z, v.w));
#pragma unroll
            for (int off = 32; off > 0; off >>= 1)
                r = fminf(r, __shfl_xor(r, off, 64));
            if (lane == 0) qs[wave] = r;
        }
        __syncthreads();
#pragma unroll
        for (int nb = 0; nb < NB; ++nb) q[nb] = qs[nb];
        // part[] is only rewritten after this barrier next depth -> safe
    }

    if (t < NB) out[br * NBATCH + bg * NB + t] = qs[t];
}

// ---------------------------------------------------------------------------
extern "C" void kernel_launch(void* const* d_in, const int* in_sizes, int n_in,
                              void* d_out, int out_size, void* d_ws, size_t ws_size,
                              hipStream_t stream) {
    const float* val = (const float*)d_in[0];
    const float* M1  = (const float*)d_in[1];
    const float* B1  = (const float*)d_in[2];
    const float* M2  = (const float*)d_in[3];
    const float* B2  = (const float*)d_in[4];
    float* ws  = (float*)d_ws;     // 8 MiB transposed copies (verified present R2)
    float* out = (float*)d_out;

    void* kargs[] = { (void*)&M1, (void*)&B1, (void*)&M2, (void*)&B2,
                      (void*)&val, (void*)&ws, (void*)&out };
    hipLaunchCooperativeKernel((const void*)fused_k, dim3(256), dim3(512),
                               kargs, 0, stream);
}

// Round 6
// 132.252 us; speedup vs baseline: 2.8810x; 2.8810x over previous
//
#include <hip/hip_runtime.h>
#include <math.h>

#define WH     256
#define NDEPTH 8
#define NBATCH 1024
#define NB     8            // batch elements per block
#define PLANE  (WH * WH)    // 65536

typedef _Float16 h2 __attribute__((ext_vector_type(2)));

// ws layout (fp16): wsh[arr][hq][d][hs][w]
//   arr: 0=M1 1=B1 2=M2 3=B2 ; hq = h>>6 (wave's 64-row block) ; hs = h&63
// Per (arr,hq): 8*64*256 = 131072 halfs = 256 KB, contiguous across depth ->
// each prop wave streams one pointer with +2 KB per 4-row chunk.
#define HQBLK  (NDEPTH * 64 * WH)   // halfs per (arr,hq) block = 131072

// ---------------------------------------------------------------------------
// Transpose + fp32->fp16 convert. 512 blocks x 256 threads.
// bid = arr(2b) | d(3b) | ht(2b) | wt(2b); 64x64 tile via fp32 LDS (pitch 65).
// ---------------------------------------------------------------------------
__global__ __launch_bounds__(256) void transpose_half_k(const float* __restrict__ M1,
                                                        const float* __restrict__ B1,
                                                        const float* __restrict__ M2,
                                                        const float* __restrict__ B2,
                                                        _Float16* __restrict__ wsh) {
    __shared__ float tile[64][65];
    const int bid = blockIdx.x;
    const int arr = bid >> 7;
    const int d   = (bid >> 4) & 7;
    const int ht  = (bid >> 2) & 3;     // h-tile == hq
    const int wt  = bid & 3;            // w-tile

    const float* src = (arr == 0) ? M1 : (arr == 1) ? B1 : (arr == 2) ? M2 : B2;
    const float* s = src + d * PLANE;
    _Float16* o = wsh + ((size_t)(arr * 4 + ht) * NDEPTH + d) * (64 * WH);

    const int t   = threadIdx.x;
    const int q16 = t >> 4;     // 0..15
    const int r16 = t & 15;     // 0..15

    // read: float4 along h (input is [d][w][h])
#pragma unroll
    for (int p = 0; p < 4; ++p) {
        const int wrow = q16 + p * 16;   // local w 0..63
        const float4 v = *(const float4*)(s + (wt * 64 + wrow) * WH + ht * 64 + r16 * 4);
        tile[wrow][r16 * 4 + 0] = v.x;
        tile[wrow][r16 * 4 + 1] = v.y;
        tile[wrow][r16 * 4 + 2] = v.z;
        tile[wrow][r16 * 4 + 3] = v.w;
    }
    __syncthreads();
    // write: 4 halfs along w (output row hs is 256 halfs contiguous)
#pragma unroll
    for (int p = 0; p < 4; ++p) {
        const int hrow = q16 + p * 16;   // local h 0..63
        const int wl   = r16 * 4;        // local w
        union { _Float16 f[4]; uint2 u; } pk;
        pk.f[0] = (_Float16)tile[wl + 0][hrow];
        pk.f[1] = (_Float16)tile[wl + 1][hrow];
        pk.f[2] = (_Float16)tile[wl + 2][hrow];
        pk.f[3] = (_Float16)tile[wl + 3][hrow];
        *(uint2*)(o + hrow * WH + wt * 64 + wl) = pk.u;
    }
}

// ---------------------------------------------------------------------------
// Prop: 256 blocks x 256 threads (4 waves, 1 block/CU).
// XCD pinning: branch = (bid&7)>>2 -> each XCD's L2 holds one branch's 2 MiB.
// Wave owns 64 h (block hq). Chunk = 4 rows = 1024 halfs; lane does two
// dwordx4 loads (rows (lane>>5) and 2+(lane>>5)). 4-deep buffer, prefetch
// distance 3, stream contiguous across depths (layout above).
// Math: v_pk_fma_f16 + v_pk_max_f16 via clang elementwise builtins
// (1 VALU instr / element).
// ---------------------------------------------------------------------------
__global__ __launch_bounds__(256, 1) void prop_h_k(const _Float16* __restrict__ wsh,
                                                   const float* __restrict__ val,
                                                   float* __restrict__ out) {
    const int bid  = blockIdx.x;
    const int g    = bid >> 3;
    const int x    = bid & 7;
    const int br   = x >> 2;
    const int bg   = g * 4 + (x & 3);     // 0..127
    const int t    = threadIdx.x;
    const int wave = t >> 6;              // 0..3 = hq
    const int lane = t & 63;

    const int arrM = br ? 2 : 0;
    const int arrB = br ? 3 : 1;
    // uint4 units: HQBLK/8 = 16384 uint4 per (arr,hq); chunk = 128 uint4
    const uint4* __restrict__ Mu = (const uint4*)wsh + (size_t)(arrM * 4 + wave) * (HQBLK / 8);
    const uint4* __restrict__ Bu = (const uint4*)wsh + (size_t)(arrB * 4 + wave) * (HQBLK / 8);

    h2 q2[NB];
#pragma unroll
    for (int nb = 0; nb < NB; ++nb) {
        const _Float16 qh = (_Float16)val[bg * NB + nb];   // block-uniform
        q2[nb].x = qh; q2[nb].y = qh;
    }

    __shared__ h2 part[8][NB][128];   // 32 KB: [virtual wave][nb][w/2]
    __shared__ float qs[NB];

    union H8 { uint4 u; h2 h[4]; };

    uint4 bm[4][2], bb[4][2];
#pragma unroll
    for (int s = 0; s < 3; ++s) {          // prologue: chunks 0..2
        bm[s][0] = Mu[s * 128 + lane]; bm[s][1] = Mu[s * 128 + 64 + lane];
        bb[s][0] = Bu[s * 128 + lane]; bb[s][1] = Bu[s * 128 + 64 + lane];
    }

    union { unsigned short us; _Float16 f; } ninf; ninf.us = 0xFC00;  // -inf fp16
    h2 NEGINF; NEGINF.x = ninf.f; NEGINF.y = ninf.f;

    for (int d = 0; d < NDEPTH; ++d) {
        h2 acc[NB][4];
#pragma unroll
        for (int nb = 0; nb < NB; ++nb)
#pragma unroll
            for (int k = 0; k < 4; ++k) acc[nb][k] = NEGINF;

#pragma unroll
        for (int c = 0; c < 16; ++c) {
            const int slot = c & 3;
            const int ps   = (c + 3) & 3;
            const int cg   = d * 16 + c + 3;      // global chunk to prefetch
            if (cg < NDEPTH * 16) {
                const uint4* mp = Mu + cg * 128 + lane;
                const uint4* bp = Bu + cg * 128 + lane;
                bm[ps][0] = mp[0]; bm[ps][1] = mp[64];
                bb[ps][0] = bp[0]; bb[ps][1] = bp[64];
            }
            H8 m0, m1, b0, b1;
            m0.u = bm[slot][0]; m1.u = bm[slot][1];
            b0.u = bb[slot][0]; b1.u = bb[slot][1];
#pragma unroll
            for (int nb = 0; nb < NB; ++nb) {
                const h2 qq = q2[nb];
#pragma unroll
                for (int k = 0; k < 4; ++k) {
                    acc[nb][k] = __builtin_elementwise_max(
                        acc[nb][k], __builtin_elementwise_fma(qq, m0.h[k], b0.h[k]));
                    acc[nb][k] = __builtin_elementwise_max(
                        acc[nb][k], __builtin_elementwise_fma(qq, m1.h[k], b1.h[k]));
                }
            }
        }

        // stage partial maxes: virtual wave vw covers a distinct 32-row subset
        const int vw  = wave * 2 + (lane >> 5);
        const int j32 = lane & 31;               // owns w = j32*8 .. j32*8+7
#pragma unroll
        for (int nb = 0; nb < NB; ++nb) {
            H8 st;
            st.h[0] = acc[nb][0]; st.h[1] = acc[nb][1];
            st.h[2] = acc[nb][2]; st.h[3] = acc[nb][3];
            *(uint4*)&part[vw][nb][j32 * 4] = st.u;
        }
        __syncthreads();

        // reduce: thread t -> nb = t>>5, j = t&31 (w block j*8..j*8+7)
        {
            const int nb = t >> 5;
            const int j  = t & 31;
            H8 v; v.u = *(const uint4*)&part[0][nb][j * 4];
#pragma unroll
            for (int s2 = 1; s2 < 8; ++s2) {
                H8 w2; w2.u = *(const uint4*)&part[s2][nb][j * 4];
#pragma unroll
                for (int k = 0; k < 4; ++k)
                    v.h[k] = __builtin_elementwise_max(v.h[k], w2.h[k]);
            }
            h2 mn = __builtin_elementwise_min(
                        __builtin_elementwise_min(v.h[0], v.h[1]),
                        __builtin_elementwise_min(v.h[2], v.h[3]));
            float r = fminf((float)mn.x, (float)mn.y);
#pragma unroll
            for (int off = 16; off > 0; off >>= 1)
                r = fminf(r, __shfl_xor(r, off, 32));   // min within 32-lane group
            if (j == 0) qs[nb] = r;
        }
        __syncthreads();
#pragma unroll
        for (int nb = 0; nb < NB; ++nb) {
            const _Float16 qh = (_Float16)qs[nb];
            q2[nb].x = qh; q2[nb].y = qh;
        }
        // part[] rewritten only after this barrier next depth -> safe
    }

    if (t < NB) out[br * NBATCH + bg * NB + t] = qs[t];
}

// ---------------------------------------------------------------------------
extern "C" void kernel_launch(void* const* d_in, const int* in_sizes, int n_in,
                              void* d_out, int out_size, void* d_ws, size_t ws_size,
                              hipStream_t stream) {
    const float* val = (const float*)d_in[0];
    const float* M1  = (const float*)d_in[1];
    const float* B1  = (const float*)d_in[2];
    const float* M2  = (const float*)d_in[3];
    const float* B2  = (const float*)d_in[4];
    float*    out = (float*)d_out;
    _Float16* wsh = (_Float16*)d_ws;   // needs 4 MiB (ws >= 8 MiB verified R2)

    transpose_half_k<<<dim3(512), dim3(256), 0, stream>>>(M1, B1, M2, B2, wsh);
    prop_h_k<<<dim3(256), dim3(256), 0, stream>>>(wsh, val, out);
}